// Round 11
// baseline (338.934 us; speedup 1.0000x reference)
//
#include <hip/hip_runtime.h>
#include <math.h>

// Bahdanau attention, fp32. B=4, TQ=TV=256, H=D=512, U=256.
// out = [context (4*256*512)] ++ [attn (4*256*256)]
//
// tanh(x) = 1 - 2/(e^{2x}+1); e^{2(q+v)} = e^{2q}*e^{2v}.
// proj_mfma: bf16 MFMA GEMMs -> Eq[q][u], EvT[u][vg] with exp2 epilogue.
// score_softmax: s_load operands + pk-fma; measured ~1us/rep (R10 NREP=8).
// context_gemm: attn @ values.
//
// *** Measurement round #2: PROJ_NREP=16 / CTX_NREP=16 in-kernel repeats
// (both idempotent) so BOTH kernels surface above the ~39us ws-poison fills
// in the top-5 table with exact per-rep duration (= dur/16) and counters.
// R10 established score ~1us/rep; ~30us of the 42us baseline is still
// unattributed (context? proj? launch gaps?). This round pins it. ***

typedef float f4 __attribute__((ext_vector_type(4)));
typedef float f2 __attribute__((ext_vector_type(2)));
typedef __attribute__((ext_vector_type(8))) short s8v;            // 8 bf16
typedef __attribute__((ext_vector_type(8))) unsigned short u8v;

#define B_    4
#define TQ_   256
#define TV_   256
#define D_    512
#define U_    256
#define KDIM  512          // H == D == 512
#define MROWS 1024         // B*TQ == B*TV

#define PROJ_NREP 16       // measurement multiplier, proj_mfma
#define CTX_NREP  16       // measurement multiplier, context_gemm

#define C2LOG2E 2.8853900817779268f   // 2*log2(e)

// ws layout (floats): Eq [1024][256] at 0 | EvT [256][1024] at 262144
#define EQ_OFF  0
#define EVT_OFF 262144

#if __has_builtin(__builtin_amdgcn_exp2f)
#define EXP2F(x) __builtin_amdgcn_exp2f(x)
#else
#define EXP2F(x) exp2f(x)
#endif
#if __has_builtin(__builtin_amdgcn_rcpf)
#define RCPF(x) __builtin_amdgcn_rcpf(x)
#else
#define RCPF(x) (1.0f / (x))
#endif

__device__ __forceinline__ unsigned short f2bf(float f) {   // RNE f32->bf16
    union { float f; unsigned u; } v; v.f = f;
    return (unsigned short)((v.u + 0x7FFF + ((v.u >> 16) & 1)) >> 16);
}

// ---------------- bf16 MFMA projection GEMMs + exp2 epilogue ----------------
// blockIdx.y = proj. 64x64 tile, 256 thr (4 waves), K=512, dbuf LDS.
__global__ __launch_bounds__(256) void proj_mfma(
    const float* __restrict__ query, const float* __restrict__ values,
    const float* __restrict__ W1, const float* __restrict__ b1,
    const float* __restrict__ W2, const float* __restrict__ b2,
    float* __restrict__ ws)
{
    __shared__ unsigned short Al[2][64][40];
    __shared__ unsigned short Bl[2][64][40];

    const int tid  = threadIdx.x;
    const int proj = blockIdx.y;
    const int x    = blockIdx.x;

    int m0, n0;
    if (proj == 0) { m0 = (x >> 2) * 64; n0 = (x & 3) * 64; }
    else           { m0 = (x & 3) * 64;  n0 = (x >> 2) * 64; }

    const int sr = tid >> 2;          // staging row 0..63
    const int sk = (tid & 3) * 8;     // k-segment

    const float* dptr = (proj ? values + (size_t)(n0 + sr) * KDIM
                              : query  + (size_t)(m0 + sr) * KDIM) + sk;
    const float* tptr = (proj ? W2 + (m0 + sr) : W1 + (n0 + sr))
                        + (size_t)sk * U_;

    f4 d0, d1;
    float tv0, tv1, tv2, tv3, tv4, tv5, tv6, tv7;

#define LOADR(S)                                                        \
    do {                                                                \
        const float* dp = dptr + (size_t)(S) * 32;                      \
        d0 = *(const f4*)(dp);                                          \
        d1 = *(const f4*)(dp + 4);                                      \
        const float* tp = tptr + (size_t)(S) * 32 * U_;                 \
        tv0 = tp[0];       tv1 = tp[U_];       tv2 = tp[2 * U_];        \
        tv3 = tp[3 * U_];  tv4 = tp[4 * U_];   tv5 = tp[5 * U_];        \
        tv6 = tp[6 * U_];  tv7 = tp[7 * U_];                            \
    } while (0)

#define WRITEB(BUF)                                                     \
    do {                                                                \
        u8v dd, tt;                                                     \
        dd[0] = f2bf(d0[0]); dd[1] = f2bf(d0[1]);                       \
        dd[2] = f2bf(d0[2]); dd[3] = f2bf(d0[3]);                       \
        dd[4] = f2bf(d1[0]); dd[5] = f2bf(d1[1]);                       \
        dd[6] = f2bf(d1[2]); dd[7] = f2bf(d1[3]);                       \
        tt[0] = f2bf(tv0); tt[1] = f2bf(tv1); tt[2] = f2bf(tv2);        \
        tt[3] = f2bf(tv3); tt[4] = f2bf(tv4); tt[5] = f2bf(tv5);        \
        tt[6] = f2bf(tv6); tt[7] = f2bf(tv7);                           \
        unsigned short* ddst = proj ? &Bl[BUF][sr][sk] : &Al[BUF][sr][sk]; \
        unsigned short* tdst = proj ? &Al[BUF][sr][sk] : &Bl[BUF][sr][sk]; \
        *(u8v*)ddst = dd;                                               \
        *(u8v*)tdst = tt;                                               \
    } while (0)

    const int w  = tid >> 6;          // wave 0..3 -> rows w*16..+15
    const int l  = tid & 63;
    const int fr = l & 15;
    const int fk = (l >> 4) * 8;
    const int orow  = m0 + w * 16 + (l >> 4) * 4;
    const int ocol0 = n0 + (l & 15);

    #pragma unroll 1
    for (int rep = 0; rep < PROJ_NREP; ++rep) {
        f4 acc0 = {}, acc1 = {}, acc2 = {}, acc3 = {};

        // cross-rep safety: rep n+1 WRITEB(0) touches buf0 while the slowest
        // wave of rep n can only be in s=15 compute, which reads buf1.
        LOADR(0);
        WRITEB(0);

        for (int s = 0; s < 16; ++s) {
            __syncthreads();
            if (s + 1 < 16) LOADR(s + 1);
            {
                const int bu = s & 1;
                s8v af  = *(const s8v*)&Al[bu][w * 16 + fr][fk];
                s8v bf0 = *(const s8v*)&Bl[bu][fr][fk];
                s8v bf1 = *(const s8v*)&Bl[bu][16 + fr][fk];
                s8v bf2 = *(const s8v*)&Bl[bu][32 + fr][fk];
                s8v bf3 = *(const s8v*)&Bl[bu][48 + fr][fk];
                acc0 = __builtin_amdgcn_mfma_f32_16x16x32_bf16(af, bf0, acc0, 0, 0, 0);
                acc1 = __builtin_amdgcn_mfma_f32_16x16x32_bf16(af, bf1, acc1, 0, 0, 0);
                acc2 = __builtin_amdgcn_mfma_f32_16x16x32_bf16(af, bf2, acc2, 0, 0, 0);
                acc3 = __builtin_amdgcn_mfma_f32_16x16x32_bf16(af, bf3, acc3, 0, 0, 0);
            }
            if (s + 1 < 16) WRITEB((s + 1) & 1);
        }

        if (proj == 0) {
            float* E = ws + EQ_OFF;       // Eq[1024][256]
            #pragma unroll
            for (int nt = 0; nt < 4; ++nt) {
                const int n = ocol0 + nt * 16;
                const float bias = b1[n];
                const f4 a = nt == 0 ? acc0 : nt == 1 ? acc1 : nt == 2 ? acc2 : acc3;
                #pragma unroll
                for (int r = 0; r < 4; ++r)
                    E[(size_t)(orow + r) * U_ + n] =
                        EXP2F((a[r] + bias) * C2LOG2E);
            }
        } else {
            float* E = ws + EVT_OFF;      // EvT[256][1024]
            #pragma unroll
            for (int nt = 0; nt < 4; ++nt) {
                const int n = ocol0 + nt * 16;
                const f4 a = nt == 0 ? acc0 : nt == 1 ? acc1 : nt == 2 ? acc2 : acc3;
                #pragma unroll
                for (int r = 0; r < 4; ++r)
                    E[(size_t)(orow + r) * MROWS + n] =
                        EXP2F((a[r] + b2[orow + r]) * C2LOG2E);
            }
        }
        asm volatile("" ::: "memory");   // reps must re-issue loads/stores
    }
#undef LOADR
#undef WRITEB
}

// ---------------- score + softmax (v2, NREP reverted to 1) ----------------
// Block = (b, 2 q-rows), 256 threads. Thread owns v = tid.
// eq/vw via block-uniform global loads (s_load); f2 pk-fma math;
// EvT 8-deep dbuf vector loads. Measured ~1us/rep (R10).
__global__ __launch_bounds__(256) void score_softmax(
    const float* __restrict__ Vw, const float* __restrict__ ws,
    float* __restrict__ out)
{
    __shared__ float redmin[4][2];
    __shared__ float redsum[4][2];

    const int tid = threadIdx.x;
    const int b  = blockIdx.y;
    const int q0 = blockIdx.x * 2;

    const float* eq0 = ws + EQ_OFF + (size_t)(b * TQ_ + q0) * U_;   // uniform
    const float* eq1 = eq0 + U_;                                    // uniform
    const float* evp = ws + EVT_OFF + (size_t)b * TV_ + tid;        // per-lane
    float* attn = out + (size_t)B_ * TQ_ * D_ + (size_t)(b * TQ_ + q0) * TV_;

    float evA[8], evB[8];
    #pragma unroll
    for (int i = 0; i < 8; ++i) evA[i] = evp[(size_t)i * MROWS];

    f2 p = {0.f, 0.f};
    const f2 one = {1.0f, 1.0f};

#define SGRP(BUF, G)                                                    \
    _Pragma("unroll")                                                   \
    for (int i = 0; i < 8; ++i) {                                       \
        const int u = (G) * 8 + i;                                      \
        f2 eq = {eq0[u], eq1[u]};      /* s_load pair */                \
        f2 ev2 = {BUF[i], BUF[i]};                                      \
        f2 den = eq * ev2 + one;       /* v_pk_fma_f32 */               \
        f2 r = {RCPF(den.x), RCPF(den.y)};                              \
        f2 wv = {Vw[u], Vw[u]};        /* s_load */                     \
        p = wv * r + p;                /* v_pk_fma_f32 */               \
    }

    #pragma unroll
    for (int g = 0; g < 32; g += 2) {
        #pragma unroll
        for (int i = 0; i < 8; ++i)
            evB[i] = evp[(size_t)((g + 1) * 8 + i) * MROWS];
        SGRP(evA, g)
        if (g + 2 < 32) {
            #pragma unroll
            for (int i = 0; i < 8; ++i)
                evA[i] = evp[(size_t)((g + 2) * 8 + i) * MROWS];
        }
        SGRP(evB, g + 1)
    }
#undef SGRP

    // softmax over v (score = const - 2p: max score = min p)
    const int w = tid >> 6, lane = tid & 63;
    float m0 = p.x, m1 = p.y;
    #pragma unroll
    for (int off = 32; off; off >>= 1) {
        m0 = fminf(m0, __shfl_xor(m0, off));
        m1 = fminf(m1, __shfl_xor(m1, off));
    }
    if (lane == 0) { redmin[w][0] = m0; redmin[w][1] = m1; }
    __syncthreads();
    m0 = fminf(fminf(redmin[0][0], redmin[1][0]),
               fminf(redmin[2][0], redmin[3][0]));
    m1 = fminf(fminf(redmin[0][1], redmin[1][1]),
               fminf(redmin[2][1], redmin[3][1]));

    float e0 = EXP2F((m0 - p.x) * C2LOG2E);
    float e1 = EXP2F((m1 - p.y) * C2LOG2E);

    float s0 = e0, s1 = e1;
    #pragma unroll
    for (int off = 32; off; off >>= 1) {
        s0 += __shfl_xor(s0, off);
        s1 += __shfl_xor(s1, off);
    }
    if (lane == 0) { redsum[w][0] = s0; redsum[w][1] = s1; }
    __syncthreads();
    s0 = redsum[0][0] + redsum[1][0] + redsum[2][0] + redsum[3][0];
    s1 = redsum[0][1] + redsum[1][1] + redsum[2][1] + redsum[3][1];

    attn[tid]       = e0 * (1.0f / s0);   // exact division
    attn[TV_ + tid] = e1 * (1.0f / s1);
}

// ---------------- context: attn @ values ----------------
// Block = (b, 4 q-rows), 256 threads. Thread owns d-pair, loops all v.
__global__ __launch_bounds__(256) void context_gemm(
    const float* __restrict__ values, float* __restrict__ out)
{
    __shared__ __align__(16) f4 apk[TV_];

    const int tid = threadIdx.x;
    const int b  = blockIdx.y;
    const int q0 = blockIdx.x * 4;

    const float* at = out + (size_t)B_ * TQ_ * D_ + (size_t)(b * TQ_ + q0) * TV_;
    const f2* vp = (const f2*)(values + (size_t)b * TV_ * D_) + tid;
    float* orow = out + (size_t)(b * TQ_ + q0) * D_ + 2 * tid;

    #pragma unroll 1
    for (int rep = 0; rep < CTX_NREP; ++rep) {
        apk[tid] = f4{at[tid], at[TV_ + tid], at[2 * TV_ + tid], at[3 * TV_ + tid]};

        f2 bufA[8], bufB[8];
        #pragma unroll
        for (int i = 0; i < 8; ++i) bufA[i] = vp[(size_t)i * (D_ / 2)];

        __syncthreads();

        f2 acc0 = {0.f, 0.f}, acc1 = {0.f, 0.f};
        f2 acc2 = {0.f, 0.f}, acc3 = {0.f, 0.f};

#define CGRP(BUF, G)                                                    \
        _Pragma("unroll")                                               \
        for (int i = 0; i < 8; ++i) {                                   \
            f4 a = apk[(G) * 8 + i];                                    \
            f2 val = BUF[i];                                            \
            acc0 += a.x * val;                                          \
            acc1 += a.y * val;                                          \
            acc2 += a.z * val;                                          \
            acc3 += a.w * val;                                          \
        }

        #pragma unroll
        for (int g = 0; g < 32; g += 2) {
            #pragma unroll
            for (int i = 0; i < 8; ++i)
                bufB[i] = vp[(size_t)((g + 1) * 8 + i) * (D_ / 2)];
            CGRP(bufA, g)
            if (g + 2 < 32) {
                #pragma unroll
                for (int i = 0; i < 8; ++i)
                    bufA[i] = vp[(size_t)((g + 2) * 8 + i) * (D_ / 2)];
            }
            CGRP(bufB, g + 1)
        }
#undef CGRP

        *(f2*)(orow)          = acc0;
        *(f2*)(orow + D_)     = acc1;
        *(f2*)(orow + 2 * D_) = acc2;
        *(f2*)(orow + 3 * D_) = acc3;

        __syncthreads();                  // apk rewrite next rep
        asm volatile("" ::: "memory");    // reps must re-issue loads
    }
}

extern "C" void kernel_launch(void* const* d_in, const int* in_sizes, int n_in,
                              void* d_out, int out_size, void* d_ws, size_t ws_size,
                              hipStream_t stream) {
    const float* query  = (const float*)d_in[0];
    const float* values = (const float*)d_in[1];
    const float* W1     = (const float*)d_in[2];
    const float* b1     = (const float*)d_in[3];
    const float* W2     = (const float*)d_in[4];
    const float* b2     = (const float*)d_in[5];
    const float* Vw     = (const float*)d_in[6];
    float* out = (float*)d_out;
    float* ws  = (float*)d_ws;

    proj_mfma<<<dim3(64, 2), 256, 0, stream>>>(query, values, W1, b1, W2, b2, ws);
    score_softmax<<<dim3(TQ_ / 2, B_), 256, 0, stream>>>(Vw, ws, out);
    context_gemm<<<dim3(TQ_ / 4, B_), 256, 0, stream>>>(values, out);
}

// Round 12
// 41.171 us; speedup vs baseline: 8.2322x; 8.2322x over previous
//
#include <hip/hip_runtime.h>
#include <math.h>

// Bahdanau attention, fp32. B=4, TQ=TV=256, H=D=512, U=256.
// out = [context (4*256*512)] ++ [attn (4*256*256)]
//
// tanh(x) = 1 - 2/(e^{2x}+1); e^{2(q+v)} = e^{2q}*e^{2v}.
// proj_mfma: bf16 MFMA GEMMs -> Eq[q][u], EvT[u][vg] with exp2 epilogue.
// score_softmax: s_load operands + pk-fma; ~1us (R10 NREP measurement).
// ctx_mfma: context = attn @ values as bf16 MFMA GEMM (R11 measured the old
//   VALU context_gemm at 13.2us/rep: VGPR=256, 1 wave/SIMD, zero TLP,
//   latency-exposed. MFMA: 64x64 tile K=256, ~16MB L2 traffic vs 128MB).
//   Error: softmax is near-uniform (weights x0.02) -> ||attn||_2 ~ 1/16;
//   bf16 attn/values adds ~1.4e-4 abs, negligible vs existing 2e-3.

typedef float f4 __attribute__((ext_vector_type(4)));
typedef float f2 __attribute__((ext_vector_type(2)));
typedef __attribute__((ext_vector_type(8))) short s8v;            // 8 bf16
typedef __attribute__((ext_vector_type(8))) unsigned short u8v;

#define B_    4
#define TQ_   256
#define TV_   256
#define D_    512
#define U_    256
#define KDIM  512          // H == D == 512
#define MROWS 1024         // B*TQ == B*TV

#define C2LOG2E 2.8853900817779268f   // 2*log2(e)

// ws layout (floats): Eq [1024][256] at 0 | EvT [256][1024] at 262144
#define EQ_OFF  0
#define EVT_OFF 262144

#if __has_builtin(__builtin_amdgcn_exp2f)
#define EXP2F(x) __builtin_amdgcn_exp2f(x)
#else
#define EXP2F(x) exp2f(x)
#endif
#if __has_builtin(__builtin_amdgcn_rcpf)
#define RCPF(x) __builtin_amdgcn_rcpf(x)
#else
#define RCPF(x) (1.0f / (x))
#endif

__device__ __forceinline__ unsigned short f2bf(float f) {   // RNE f32->bf16
    union { float f; unsigned u; } v; v.f = f;
    return (unsigned short)((v.u + 0x7FFF + ((v.u >> 16) & 1)) >> 16);
}

// ---------------- bf16 MFMA projection GEMMs + exp2 epilogue ----------------
// blockIdx.y = proj. 64x64 tile, 256 thr (4 waves), K=512, dbuf LDS.
__global__ __launch_bounds__(256) void proj_mfma(
    const float* __restrict__ query, const float* __restrict__ values,
    const float* __restrict__ W1, const float* __restrict__ b1,
    const float* __restrict__ W2, const float* __restrict__ b2,
    float* __restrict__ ws)
{
    __shared__ unsigned short Al[2][64][40];
    __shared__ unsigned short Bl[2][64][40];

    const int tid  = threadIdx.x;
    const int proj = blockIdx.y;
    const int x    = blockIdx.x;

    int m0, n0;
    if (proj == 0) { m0 = (x >> 2) * 64; n0 = (x & 3) * 64; }
    else           { m0 = (x & 3) * 64;  n0 = (x >> 2) * 64; }

    const int sr = tid >> 2;          // staging row 0..63
    const int sk = (tid & 3) * 8;     // k-segment

    const float* dptr = (proj ? values + (size_t)(n0 + sr) * KDIM
                              : query  + (size_t)(m0 + sr) * KDIM) + sk;
    const float* tptr = (proj ? W2 + (m0 + sr) : W1 + (n0 + sr))
                        + (size_t)sk * U_;

    f4 d0, d1;
    float tv0, tv1, tv2, tv3, tv4, tv5, tv6, tv7;

#define LOADR(S)                                                        \
    do {                                                                \
        const float* dp = dptr + (size_t)(S) * 32;                      \
        d0 = *(const f4*)(dp);                                          \
        d1 = *(const f4*)(dp + 4);                                      \
        const float* tp = tptr + (size_t)(S) * 32 * U_;                 \
        tv0 = tp[0];       tv1 = tp[U_];       tv2 = tp[2 * U_];        \
        tv3 = tp[3 * U_];  tv4 = tp[4 * U_];   tv5 = tp[5 * U_];        \
        tv6 = tp[6 * U_];  tv7 = tp[7 * U_];                            \
    } while (0)

#define WRITEB(BUF)                                                     \
    do {                                                                \
        u8v dd, tt;                                                     \
        dd[0] = f2bf(d0[0]); dd[1] = f2bf(d0[1]);                       \
        dd[2] = f2bf(d0[2]); dd[3] = f2bf(d0[3]);                       \
        dd[4] = f2bf(d1[0]); dd[5] = f2bf(d1[1]);                       \
        dd[6] = f2bf(d1[2]); dd[7] = f2bf(d1[3]);                       \
        tt[0] = f2bf(tv0); tt[1] = f2bf(tv1); tt[2] = f2bf(tv2);        \
        tt[3] = f2bf(tv3); tt[4] = f2bf(tv4); tt[5] = f2bf(tv5);        \
        tt[6] = f2bf(tv6); tt[7] = f2bf(tv7);                           \
        unsigned short* ddst = proj ? &Bl[BUF][sr][sk] : &Al[BUF][sr][sk]; \
        unsigned short* tdst = proj ? &Al[BUF][sr][sk] : &Bl[BUF][sr][sk]; \
        *(u8v*)ddst = dd;                                               \
        *(u8v*)tdst = tt;                                               \
    } while (0)

    f4 acc0 = {}, acc1 = {}, acc2 = {}, acc3 = {};

    const int w  = tid >> 6;          // wave 0..3 -> rows w*16..+15
    const int l  = tid & 63;
    const int fr = l & 15;
    const int fk = (l >> 4) * 8;

    LOADR(0);
    WRITEB(0);

    for (int s = 0; s < 16; ++s) {
        __syncthreads();
        if (s + 1 < 16) LOADR(s + 1);
        {
            const int bu = s & 1;
            s8v af  = *(const s8v*)&Al[bu][w * 16 + fr][fk];
            s8v bf0 = *(const s8v*)&Bl[bu][fr][fk];
            s8v bf1 = *(const s8v*)&Bl[bu][16 + fr][fk];
            s8v bf2 = *(const s8v*)&Bl[bu][32 + fr][fk];
            s8v bf3 = *(const s8v*)&Bl[bu][48 + fr][fk];
            acc0 = __builtin_amdgcn_mfma_f32_16x16x32_bf16(af, bf0, acc0, 0, 0, 0);
            acc1 = __builtin_amdgcn_mfma_f32_16x16x32_bf16(af, bf1, acc1, 0, 0, 0);
            acc2 = __builtin_amdgcn_mfma_f32_16x16x32_bf16(af, bf2, acc2, 0, 0, 0);
            acc3 = __builtin_amdgcn_mfma_f32_16x16x32_bf16(af, bf3, acc3, 0, 0, 0);
        }
        if (s + 1 < 16) WRITEB((s + 1) & 1);
    }
#undef LOADR
#undef WRITEB

    const int orow  = m0 + w * 16 + (l >> 4) * 4;
    const int ocol0 = n0 + (l & 15);

    if (proj == 0) {
        float* E = ws + EQ_OFF;       // Eq[1024][256]
        #pragma unroll
        for (int nt = 0; nt < 4; ++nt) {
            const int n = ocol0 + nt * 16;
            const float bias = b1[n];
            const f4 a = nt == 0 ? acc0 : nt == 1 ? acc1 : nt == 2 ? acc2 : acc3;
            #pragma unroll
            for (int r = 0; r < 4; ++r)
                E[(size_t)(orow + r) * U_ + n] =
                    EXP2F((a[r] + bias) * C2LOG2E);
        }
    } else {
        float* E = ws + EVT_OFF;      // EvT[256][1024]
        #pragma unroll
        for (int nt = 0; nt < 4; ++nt) {
            const int n = ocol0 + nt * 16;
            const f4 a = nt == 0 ? acc0 : nt == 1 ? acc1 : nt == 2 ? acc2 : acc3;
            #pragma unroll
            for (int r = 0; r < 4; ++r)
                E[(size_t)(orow + r) * MROWS + n] =
                    EXP2F((a[r] + b2[orow + r]) * C2LOG2E);
        }
    }
}

// ---------------- score + softmax ----------------
// Block = (b, 2 q-rows), 256 threads. Thread owns v = tid.
// eq/vw via block-uniform global loads (s_load); f2 pk-fma math;
// EvT 8-deep dbuf vector loads. Measured ~1us (R10).
__global__ __launch_bounds__(256) void score_softmax(
    const float* __restrict__ Vw, const float* __restrict__ ws,
    float* __restrict__ out)
{
    __shared__ float redmin[4][2];
    __shared__ float redsum[4][2];

    const int tid = threadIdx.x;
    const int b  = blockIdx.y;
    const int q0 = blockIdx.x * 2;

    const float* eq0 = ws + EQ_OFF + (size_t)(b * TQ_ + q0) * U_;   // uniform
    const float* eq1 = eq0 + U_;                                    // uniform
    const float* evp = ws + EVT_OFF + (size_t)b * TV_ + tid;        // per-lane
    float* attn = out + (size_t)B_ * TQ_ * D_ + (size_t)(b * TQ_ + q0) * TV_;

    float evA[8], evB[8];
    #pragma unroll
    for (int i = 0; i < 8; ++i) evA[i] = evp[(size_t)i * MROWS];

    f2 p = {0.f, 0.f};
    const f2 one = {1.0f, 1.0f};

#define SGRP(BUF, G)                                                    \
    _Pragma("unroll")                                                   \
    for (int i = 0; i < 8; ++i) {                                       \
        const int u = (G) * 8 + i;                                      \
        f2 eq = {eq0[u], eq1[u]};      /* s_load pair */                \
        f2 ev2 = {BUF[i], BUF[i]};                                      \
        f2 den = eq * ev2 + one;       /* v_pk_fma_f32 */               \
        f2 r = {RCPF(den.x), RCPF(den.y)};                              \
        f2 wv = {Vw[u], Vw[u]};        /* s_load */                     \
        p = wv * r + p;                /* v_pk_fma_f32 */               \
    }

    #pragma unroll
    for (int g = 0; g < 32; g += 2) {
        #pragma unroll
        for (int i = 0; i < 8; ++i)
            evB[i] = evp[(size_t)((g + 1) * 8 + i) * MROWS];
        SGRP(evA, g)
        if (g + 2 < 32) {
            #pragma unroll
            for (int i = 0; i < 8; ++i)
                evA[i] = evp[(size_t)((g + 2) * 8 + i) * MROWS];
        }
        SGRP(evB, g + 1)
    }
#undef SGRP

    // softmax over v (score = const - 2p: max score = min p)
    const int w = tid >> 6, lane = tid & 63;
    float m0 = p.x, m1 = p.y;
    #pragma unroll
    for (int off = 32; off; off >>= 1) {
        m0 = fminf(m0, __shfl_xor(m0, off));
        m1 = fminf(m1, __shfl_xor(m1, off));
    }
    if (lane == 0) { redmin[w][0] = m0; redmin[w][1] = m1; }
    __syncthreads();
    m0 = fminf(fminf(redmin[0][0], redmin[1][0]),
               fminf(redmin[2][0], redmin[3][0]));
    m1 = fminf(fminf(redmin[0][1], redmin[1][1]),
               fminf(redmin[2][1], redmin[3][1]));

    float e0 = EXP2F((m0 - p.x) * C2LOG2E);
    float e1 = EXP2F((m1 - p.y) * C2LOG2E);

    float s0 = e0, s1 = e1;
    #pragma unroll
    for (int off = 32; off; off >>= 1) {
        s0 += __shfl_xor(s0, off);
        s1 += __shfl_xor(s1, off);
    }
    if (lane == 0) { redsum[w][0] = s0; redsum[w][1] = s1; }
    __syncthreads();
    s0 = redsum[0][0] + redsum[1][0] + redsum[2][0] + redsum[3][0];
    s1 = redsum[0][1] + redsum[1][1] + redsum[2][1] + redsum[3][1];

    attn[tid]       = e0 * (1.0f / s0);   // exact division
    attn[TV_ + tid] = e1 * (1.0f / s1);
}

// ---------------- context = attn @ values, bf16 MFMA ----------------
// Per batch: C[256 q][512 d] = attn[256 q][256 v] @ values[256 v][512 d].
// 64x64 tile, K=256 (8 dbuf steps of 32), 256 thr (4 waves).
// A path (direct): attn rows, k(v)-contiguous. B path (trans): values
// column n0+sr, stride D_ per k. Same skeleton/frag layout as proj_mfma.
// blockIdx.x: mtile = x>>3 (4), ntile = x&7 (8). blockIdx.y = b.
__global__ __launch_bounds__(256) void ctx_mfma(
    const float* __restrict__ values, float* __restrict__ out)
{
    __shared__ unsigned short Al[2][64][40];
    __shared__ unsigned short Bl[2][64][40];

    const int tid = threadIdx.x;
    const int b   = blockIdx.y;
    const int x   = blockIdx.x;
    const int m0  = (x >> 3) * 64;    // q-tile
    const int n0  = (x & 7) * 64;     // d-tile

    const int sr = tid >> 2;          // staging row 0..63
    const int sk = (tid & 3) * 8;     // k-segment

    const float* attn = out + (size_t)B_ * TQ_ * D_ + (size_t)b * TQ_ * TV_;
    const float* valb = values + (size_t)b * TV_ * D_;

    const float* dptr = attn + (size_t)(m0 + sr) * TV_ + sk;      // A rows
    const float* tptr = valb + (n0 + sr) + (size_t)sk * D_;       // B cols

    f4 d0, d1;
    float tv0, tv1, tv2, tv3, tv4, tv5, tv6, tv7;

#define LOADC(S)                                                        \
    do {                                                                \
        const float* dp = dptr + (size_t)(S) * 32;                      \
        d0 = *(const f4*)(dp);                                          \
        d1 = *(const f4*)(dp + 4);                                      \
        const float* tp = tptr + (size_t)(S) * 32 * D_;                 \
        tv0 = tp[0];       tv1 = tp[D_];       tv2 = tp[2 * D_];        \
        tv3 = tp[3 * D_];  tv4 = tp[4 * D_];   tv5 = tp[5 * D_];        \
        tv6 = tp[6 * D_];  tv7 = tp[7 * D_];                            \
    } while (0)

#define WRITEC(BUF)                                                     \
    do {                                                                \
        u8v dd, tt;                                                     \
        dd[0] = f2bf(d0[0]); dd[1] = f2bf(d0[1]);                       \
        dd[2] = f2bf(d0[2]); dd[3] = f2bf(d0[3]);                       \
        dd[4] = f2bf(d1[0]); dd[5] = f2bf(d1[1]);                       \
        dd[6] = f2bf(d1[2]); dd[7] = f2bf(d1[3]);                       \
        tt[0] = f2bf(tv0); tt[1] = f2bf(tv1); tt[2] = f2bf(tv2);        \
        tt[3] = f2bf(tv3); tt[4] = f2bf(tv4); tt[5] = f2bf(tv5);        \
        tt[6] = f2bf(tv6); tt[7] = f2bf(tv7);                           \
        *(u8v*)&Al[BUF][sr][sk] = dd;                                   \
        *(u8v*)&Bl[BUF][sr][sk] = tt;                                   \
    } while (0)

    f4 acc0 = {}, acc1 = {}, acc2 = {}, acc3 = {};

    const int w  = tid >> 6;
    const int l  = tid & 63;
    const int fr = l & 15;
    const int fk = (l >> 4) * 8;

    LOADC(0);
    WRITEC(0);

    for (int s = 0; s < 8; ++s) {     // K = 256
        __syncthreads();
        if (s + 1 < 8) LOADC(s + 1);
        {
            const int bu = s & 1;
            s8v af  = *(const s8v*)&Al[bu][w * 16 + fr][fk];
            s8v bf0 = *(const s8v*)&Bl[bu][fr][fk];
            s8v bf1 = *(const s8v*)&Bl[bu][16 + fr][fk];
            s8v bf2 = *(const s8v*)&Bl[bu][32 + fr][fk];
            s8v bf3 = *(const s8v*)&Bl[bu][48 + fr][fk];
            acc0 = __builtin_amdgcn_mfma_f32_16x16x32_bf16(af, bf0, acc0, 0, 0, 0);
            acc1 = __builtin_amdgcn_mfma_f32_16x16x32_bf16(af, bf1, acc1, 0, 0, 0);
            acc2 = __builtin_amdgcn_mfma_f32_16x16x32_bf16(af, bf2, acc2, 0, 0, 0);
            acc3 = __builtin_amdgcn_mfma_f32_16x16x32_bf16(af, bf3, acc3, 0, 0, 0);
        }
        if (s + 1 < 8) WRITEC((s + 1) & 1);
    }
#undef LOADC
#undef WRITEC

    // C/D: col = l&15 (+16*nt), row = (l>>4)*4 + r
    const int orow  = m0 + w * 16 + (l >> 4) * 4;
    const int ocol0 = n0 + (l & 15);
    float* C = out + (size_t)b * TQ_ * D_;

    #pragma unroll
    for (int nt = 0; nt < 4; ++nt) {
        const int n = ocol0 + nt * 16;
        const f4 a = nt == 0 ? acc0 : nt == 1 ? acc1 : nt == 2 ? acc2 : acc3;
        #pragma unroll
        for (int r = 0; r < 4; ++r)
            C[(size_t)(orow + r) * D_ + n] = a[r];
    }
}

extern "C" void kernel_launch(void* const* d_in, const int* in_sizes, int n_in,
                              void* d_out, int out_size, void* d_ws, size_t ws_size,
                              hipStream_t stream) {
    const float* query  = (const float*)d_in[0];
    const float* values = (const float*)d_in[1];
    const float* W1     = (const float*)d_in[2];
    const float* b1     = (const float*)d_in[3];
    const float* W2     = (const float*)d_in[4];
    const float* b2     = (const float*)d_in[5];
    const float* Vw     = (const float*)d_in[6];
    float* out = (float*)d_out;
    float* ws  = (float*)d_ws;

    proj_mfma<<<dim3(64, 2), 256, 0, stream>>>(query, values, W1, b1, W2, b2, ws);
    score_softmax<<<dim3(TQ_ / 2, B_), 256, 0, stream>>>(Vw, ws, out);
    ctx_mfma<<<dim3(32, B_), 256, 0, stream>>>(values, out);
}

// Round 13
// 40.781 us; speedup vs baseline: 8.3111x; 1.0096x over previous
//
#include <hip/hip_runtime.h>
#include <math.h>

// Bahdanau attention, fp32. B=4, TQ=TV=256, H=D=512, U=256.
// out = [context (4*256*512)] ++ [attn (4*256*256)]
//
// tanh(x) = 1 - 2/(e^{2x}+1); e^{2(q+v)} = e^{2q}*e^{2v}.
// proj_mfma: bf16 MFMA GEMMs -> Eq[q][u], EvT[u][vg] with exp2 epilogue.
// score_softmax: s_load operands + pk-fma; ~1us (R10 NREP measurement).
// ctx_mfma: context = attn @ values, bf16 MFMA.
//
// R13: 32x32 tiles, 4x the blocks. R12 ledger: proj=6.6us, ctx~12us, both at
// 128 blocks/256 CUs = half chip idle + 1 wave/SIMD -> every K-step pays full
// L2 latency (~300cyc) with only ~100cyc of MFMA to hide it. 32x32 tiles ->
// 512 blocks each kernel = 2 blocks/CU: co-resident blocks interleave
// staging-latency with MFMA issue. LDS 10KB. One 16x16 acc per wave.

typedef float f4 __attribute__((ext_vector_type(4)));
typedef float f2 __attribute__((ext_vector_type(2)));
typedef __attribute__((ext_vector_type(8))) short s8v;            // 8 bf16
typedef __attribute__((ext_vector_type(4))) unsigned short u4v;   // 4 bf16

#define B_    4
#define TQ_   256
#define TV_   256
#define D_    512
#define U_    256
#define KDIM  512          // H == D == 512
#define MROWS 1024         // B*TQ == B*TV

#define C2LOG2E 2.8853900817779268f   // 2*log2(e)

// ws layout (floats): Eq [1024][256] at 0 | EvT [256][1024] at 262144
#define EQ_OFF  0
#define EVT_OFF 262144

#if __has_builtin(__builtin_amdgcn_exp2f)
#define EXP2F(x) __builtin_amdgcn_exp2f(x)
#else
#define EXP2F(x) exp2f(x)
#endif
#if __has_builtin(__builtin_amdgcn_rcpf)
#define RCPF(x) __builtin_amdgcn_rcpf(x)
#else
#define RCPF(x) (1.0f / (x))
#endif

__device__ __forceinline__ unsigned short f2bf(float f) {   // RNE f32->bf16
    union { float f; unsigned u; } v; v.f = f;
    return (unsigned short)((v.u + 0x7FFF + ((v.u >> 16) & 1)) >> 16);
}

// ---------------- bf16 MFMA projection GEMMs + exp2 epilogue ----------------
// 32x32 tile, K=512 (16 dbuf steps of 32), 256 thr (4 waves).
// blockIdx.y = proj.  proj0: Eq[m=q][n=u] = query @ W1 (+b1, exp2)
//                     proj1: EvT[m=u][n=v] = W2^T @ values^T (+b2, exp2)
// direct path (f4 row loads):  proj0 query rows -> Al ; proj1 values rows -> Bl
// gather path (4x strided):    proj0 W1 cols -> Bl    ; proj1 W2 cols -> Al
// Wave w: acc = 16x16 at row band (w&1)*16, col half (w>>1)*16.
__global__ __launch_bounds__(256) void proj_mfma(
    const float* __restrict__ query, const float* __restrict__ values,
    const float* __restrict__ W1, const float* __restrict__ b1,
    const float* __restrict__ W2, const float* __restrict__ b2,
    float* __restrict__ ws)
{
    __shared__ unsigned short Al[2][32][40];
    __shared__ unsigned short Bl[2][32][40];

    const int tid  = threadIdx.x;
    const int proj = blockIdx.y;
    const int x    = blockIdx.x;

    int m0, n0;
    if (proj == 0) { m0 = (x >> 3) * 32; n0 = (x & 7) * 32; }   // 32 x 8
    else           { m0 = (x & 7) * 32;  n0 = (x >> 3) * 32; }  // 8 x 32

    const int drow = tid >> 3;        // direct-path row 0..31
    const int dk   = (tid & 7) * 4;   // direct-path k offset
    // gather path uses the same decomposition: col 0..31, k offset
    const int tcol = drow;
    const int tk   = dk;

    const float* dptr = (proj ? values + (size_t)(n0 + drow) * KDIM
                              : query  + (size_t)(m0 + drow) * KDIM) + dk;
    const float* tptr = (proj ? W2 + (m0 + tcol) : W1 + (n0 + tcol))
                        + (size_t)tk * U_;

    f4 d0;
    float tv0, tv1, tv2, tv3;

#define LOADR(S)                                                        \
    do {                                                                \
        d0 = *(const f4*)(dptr + (size_t)(S) * 32);                     \
        const float* tp = tptr + (size_t)(S) * 32 * U_;                 \
        tv0 = tp[0]; tv1 = tp[U_]; tv2 = tp[2 * U_]; tv3 = tp[3 * U_];  \
    } while (0)

#define WRITEB(BUF)                                                     \
    do {                                                                \
        u4v dd, tt;                                                     \
        dd[0] = f2bf(d0[0]); dd[1] = f2bf(d0[1]);                       \
        dd[2] = f2bf(d0[2]); dd[3] = f2bf(d0[3]);                       \
        tt[0] = f2bf(tv0);   tt[1] = f2bf(tv1);                         \
        tt[2] = f2bf(tv2);   tt[3] = f2bf(tv3);                         \
        unsigned short* ddst = proj ? &Bl[BUF][drow][dk] : &Al[BUF][drow][dk]; \
        unsigned short* tdst = proj ? &Al[BUF][tcol][tk] : &Bl[BUF][tcol][tk]; \
        *(u4v*)ddst = dd;                                               \
        *(u4v*)tdst = tt;                                               \
    } while (0)

    f4 acc = {};

    const int w    = tid >> 6;        // wave 0..3
    const int l    = tid & 63;
    const int fr   = l & 15;
    const int fk   = (l >> 4) * 8;
    const int band = (w & 1) * 16;    // row band
    const int colh = (w >> 1) * 16;   // col half

    LOADR(0);
    WRITEB(0);

    for (int s = 0; s < 16; ++s) {
        __syncthreads();
        if (s + 1 < 16) LOADR(s + 1);
        {
            const int bu = s & 1;
            s8v af = *(const s8v*)&Al[bu][band + fr][fk];
            s8v bf = *(const s8v*)&Bl[bu][colh + fr][fk];
            acc = __builtin_amdgcn_mfma_f32_16x16x32_bf16(af, bf, acc, 0, 0, 0);
        }
        if (s + 1 < 16) WRITEB((s + 1) & 1);
    }
#undef LOADR
#undef WRITEB

    // C/D: col = l&15, row = (l>>4)*4 + r
    const int orow = m0 + band + (l >> 4) * 4;
    const int ocol = n0 + colh + (l & 15);

    if (proj == 0) {
        float* E = ws + EQ_OFF;       // Eq[1024][256]
        const float bias = b1[ocol];
        #pragma unroll
        for (int r = 0; r < 4; ++r)
            E[(size_t)(orow + r) * U_ + ocol] =
                EXP2F((acc[r] + bias) * C2LOG2E);
    } else {
        float* E = ws + EVT_OFF;      // EvT[256][1024]
        #pragma unroll
        for (int r = 0; r < 4; ++r)
            E[(size_t)(orow + r) * MROWS + ocol] =
                EXP2F((acc[r] + b2[orow + r]) * C2LOG2E);
    }
}

// ---------------- score + softmax (unchanged, ~1us) ----------------
// Block = (b, 2 q-rows), 256 threads. Thread owns v = tid.
__global__ __launch_bounds__(256) void score_softmax(
    const float* __restrict__ Vw, const float* __restrict__ ws,
    float* __restrict__ out)
{
    __shared__ float redmin[4][2];
    __shared__ float redsum[4][2];

    const int tid = threadIdx.x;
    const int b  = blockIdx.y;
    const int q0 = blockIdx.x * 2;

    const float* eq0 = ws + EQ_OFF + (size_t)(b * TQ_ + q0) * U_;   // uniform
    const float* eq1 = eq0 + U_;                                    // uniform
    const float* evp = ws + EVT_OFF + (size_t)b * TV_ + tid;        // per-lane
    float* attn = out + (size_t)B_ * TQ_ * D_ + (size_t)(b * TQ_ + q0) * TV_;

    float evA[8], evB[8];
    #pragma unroll
    for (int i = 0; i < 8; ++i) evA[i] = evp[(size_t)i * MROWS];

    f2 p = {0.f, 0.f};
    const f2 one = {1.0f, 1.0f};

#define SGRP(BUF, G)                                                    \
    _Pragma("unroll")                                                   \
    for (int i = 0; i < 8; ++i) {                                       \
        const int u = (G) * 8 + i;                                      \
        f2 eq = {eq0[u], eq1[u]};      /* s_load pair */                \
        f2 ev2 = {BUF[i], BUF[i]};                                      \
        f2 den = eq * ev2 + one;       /* v_pk_fma_f32 */               \
        f2 r = {RCPF(den.x), RCPF(den.y)};                              \
        f2 wv = {Vw[u], Vw[u]};        /* s_load */                     \
        p = wv * r + p;                /* v_pk_fma_f32 */               \
    }

    #pragma unroll
    for (int g = 0; g < 32; g += 2) {
        #pragma unroll
        for (int i = 0; i < 8; ++i)
            evB[i] = evp[(size_t)((g + 1) * 8 + i) * MROWS];
        SGRP(evA, g)
        if (g + 2 < 32) {
            #pragma unroll
            for (int i = 0; i < 8; ++i)
                evA[i] = evp[(size_t)((g + 2) * 8 + i) * MROWS];
        }
        SGRP(evB, g + 1)
    }
#undef SGRP

    // softmax over v (score = const - 2p: max score = min p)
    const int w = tid >> 6, lane = tid & 63;
    float m0 = p.x, m1 = p.y;
    #pragma unroll
    for (int off = 32; off; off >>= 1) {
        m0 = fminf(m0, __shfl_xor(m0, off));
        m1 = fminf(m1, __shfl_xor(m1, off));
    }
    if (lane == 0) { redmin[w][0] = m0; redmin[w][1] = m1; }
    __syncthreads();
    m0 = fminf(fminf(redmin[0][0], redmin[1][0]),
               fminf(redmin[2][0], redmin[3][0]));
    m1 = fminf(fminf(redmin[0][1], redmin[1][1]),
               fminf(redmin[2][1], redmin[3][1]));

    float e0 = EXP2F((m0 - p.x) * C2LOG2E);
    float e1 = EXP2F((m1 - p.y) * C2LOG2E);

    float s0 = e0, s1 = e1;
    #pragma unroll
    for (int off = 32; off; off >>= 1) {
        s0 += __shfl_xor(s0, off);
        s1 += __shfl_xor(s1, off);
    }
    if (lane == 0) { redsum[w][0] = s0; redsum[w][1] = s1; }
    __syncthreads();
    s0 = redsum[0][0] + redsum[1][0] + redsum[2][0] + redsum[3][0];
    s1 = redsum[0][1] + redsum[1][1] + redsum[2][1] + redsum[3][1];

    attn[tid]       = e0 * (1.0f / s0);   // exact division
    attn[TV_ + tid] = e1 * (1.0f / s1);
}

// ---------------- context = attn @ values, bf16 MFMA, 32x32 tiles ----------
// Per batch: C[256 q][512 d] = attn[256 q][256 v] @ values[256 v][512 d].
// K=256 (8 dbuf steps). Grid (128, B_): m-tile = x>>4, n-tile = x&15.
// A (direct): attn rows. B (gather): values cols, stride D_.
__global__ __launch_bounds__(256) void ctx_mfma(
    const float* __restrict__ values, float* __restrict__ out)
{
    __shared__ unsigned short Al[2][32][40];
    __shared__ unsigned short Bl[2][32][40];

    const int tid = threadIdx.x;
    const int b   = blockIdx.y;
    const int x   = blockIdx.x;
    const int m0  = (x >> 4) * 32;    // q-tile (8)
    const int n0  = (x & 15) * 32;    // d-tile (16)

    const int drow = tid >> 3;        // 0..31
    const int dk   = (tid & 7) * 4;

    const float* attn = out + (size_t)B_ * TQ_ * D_ + (size_t)b * TQ_ * TV_;
    const float* valb = values + (size_t)b * TV_ * D_;

    const float* dptr = attn + (size_t)(m0 + drow) * TV_ + dk;   // A rows
    const float* tptr = valb + (n0 + drow) + (size_t)dk * D_;    // B cols

    f4 d0;
    float tv0, tv1, tv2, tv3;

#define LOADC(S)                                                        \
    do {                                                                \
        d0 = *(const f4*)(dptr + (size_t)(S) * 32);                     \
        const float* tp = tptr + (size_t)(S) * 32 * D_;                 \
        tv0 = tp[0]; tv1 = tp[D_]; tv2 = tp[2 * D_]; tv3 = tp[3 * D_];  \
    } while (0)

#define WRITEC(BUF)                                                     \
    do {                                                                \
        u4v dd, tt;                                                     \
        dd[0] = f2bf(d0[0]); dd[1] = f2bf(d0[1]);                       \
        dd[2] = f2bf(d0[2]); dd[3] = f2bf(d0[3]);                       \
        tt[0] = f2bf(tv0);   tt[1] = f2bf(tv1);                         \
        tt[2] = f2bf(tv2);   tt[3] = f2bf(tv3);                         \
        *(u4v*)&Al[BUF][drow][dk] = dd;                                 \
        *(u4v*)&Bl[BUF][drow][dk] = tt;                                 \
    } while (0)

    f4 acc = {};

    const int w    = tid >> 6;
    const int l    = tid & 63;
    const int fr   = l & 15;
    const int fk   = (l >> 4) * 8;
    const int band = (w & 1) * 16;
    const int colh = (w >> 1) * 16;

    LOADC(0);
    WRITEC(0);

    for (int s = 0; s < 8; ++s) {     // K = 256
        __syncthreads();
        if (s + 1 < 8) LOADC(s + 1);
        {
            const int bu = s & 1;
            s8v af = *(const s8v*)&Al[bu][band + fr][fk];
            s8v bf = *(const s8v*)&Bl[bu][colh + fr][fk];
            acc = __builtin_amdgcn_mfma_f32_16x16x32_bf16(af, bf, acc, 0, 0, 0);
        }
        if (s + 1 < 8) WRITEC((s + 1) & 1);
    }
#undef LOADC
#undef WRITEC

    const int orow = m0 + band + (l >> 4) * 4;
    const int ocol = n0 + colh + (l & 15);
    float* C = out + (size_t)b * TQ_ * D_;

    #pragma unroll
    for (int r = 0; r < 4; ++r)
        C[(size_t)(orow + r) * D_ + ocol] = acc[r];
}

extern "C" void kernel_launch(void* const* d_in, const int* in_sizes, int n_in,
                              void* d_out, int out_size, void* d_ws, size_t ws_size,
                              hipStream_t stream) {
    const float* query  = (const float*)d_in[0];
    const float* values = (const float*)d_in[1];
    const float* W1     = (const float*)d_in[2];
    const float* b1     = (const float*)d_in[3];
    const float* W2     = (const float*)d_in[4];
    const float* b2     = (const float*)d_in[5];
    const float* Vw     = (const float*)d_in[6];
    float* out = (float*)d_out;
    float* ws  = (float*)d_ws;

    proj_mfma<<<dim3(256, 2), 256, 0, stream>>>(query, values, W1, b1, W2, b2, ws);
    score_softmax<<<dim3(TQ_ / 2, B_), 256, 0, stream>>>(Vw, ws, out);
    ctx_mfma<<<dim3(128, B_), 256, 0, stream>>>(values, out);
}

// Round 14
// 38.791 us; speedup vs baseline: 8.7375x; 1.0513x over previous
//
#include <hip/hip_runtime.h>
#include <math.h>

// Bahdanau attention, fp32. B=4, TQ=TV=256, H=D=512, U=256.
// out = [context (4*256*512)] ++ [attn (4*256*256)]
//
// tanh(x) = 1 - 2/(e^{2x}+1); e^{2(q+v)} = e^{2q}*e^{2v}.
// Ledger (R10/R11 NREP-measured): proj 6.6 | score 0.9 | ctx ~12 | C 21.5 fixed.
// ctx invariant at ~12us across 4 implementations + 1.1MB/rep HBM re-fetch
// (R11 counters) => hostile-memory regime (harness's 268MB/iter poison fills
// scrub L2/L3). R14: cut bytes + staging work. bf16 EvT/attn/valT in ws;
// ctx = 4-step BK=64 MFMA with pure u8v copy staging (no cvt in hot loop).

typedef float f4 __attribute__((ext_vector_type(4)));
typedef float f2 __attribute__((ext_vector_type(2)));
typedef __attribute__((ext_vector_type(8))) short s8v;            // 8 bf16
typedef __attribute__((ext_vector_type(4))) unsigned short u4v;   // 4 bf16
typedef __attribute__((ext_vector_type(8))) unsigned short u8v;   // 8 bf16

#define B_    4
#define TQ_   256
#define TV_   256
#define D_    512
#define U_    256
#define KDIM  512          // H == D == 512
#define MROWS 1024         // B*TQ == B*TV

#define C2LOG2E 2.8853900817779268f   // 2*log2(e)

// ws layout: Eq f32 [1024][256] @ byte 0 (1MB)
//            EvT bf16 [256 u][1024 vg] @ 1MB (512KB)
//            attnbf bf16 [4][256 q][256 v] @ 1.5MB (512KB)
//            valT bf16 [4][512 d][256 v] @ 2MB (1MB)
#define EVT_U16_OFF   524288
#define ATTN_U16_OFF  786432
#define VALT_U16_OFF 1048576

#if __has_builtin(__builtin_amdgcn_exp2f)
#define EXP2F(x) __builtin_amdgcn_exp2f(x)
#else
#define EXP2F(x) exp2f(x)
#endif
#if __has_builtin(__builtin_amdgcn_rcpf)
#define RCPF(x) __builtin_amdgcn_rcpf(x)
#else
#define RCPF(x) (1.0f / (x))
#endif

__device__ __forceinline__ unsigned short f2bf(float f) {   // RNE f32->bf16
    union { float f; unsigned u; } v; v.f = f;
    return (unsigned short)((v.u + 0x7FFF + ((v.u >> 16) & 1)) >> 16);
}
__device__ __forceinline__ float bf2f(unsigned short h) {
    union { unsigned u; float f; } v; v.u = (unsigned)h << 16;
    return v.f;
}

// ---------------- proj GEMMs + exp2 epilogue + valT transpose ----------------
// blockIdx.y: 0 -> Eq (f32 out), 1 -> EvT (bf16 out), 2 -> valT transpose.
// proj: 32x32 tile, K=512 (16 dbuf steps of 32), 256 thr (4 waves).
__global__ __launch_bounds__(256) void proj_mfma(
    const float* __restrict__ query, const float* __restrict__ values,
    const float* __restrict__ W1, const float* __restrict__ b1,
    const float* __restrict__ W2, const float* __restrict__ b2,
    float* __restrict__ ws)
{
    const int tid = threadIdx.x;
    const int job = blockIdx.y;

    if (job == 2) {
        // valT[b][d][v] = bf16(values[b][v][d]). 65536 threads, 8 v's each.
        // Reads coalesced (lane-consecutive d); writes 16B chunks.
        const int idx = blockIdx.x * 256 + tid;   // 0..65535
        const int d   = idx & 511;
        const int vg  = (idx >> 9) & 31;          // v-group of 8
        const int b   = idx >> 14;
        const float* src = values + ((size_t)b * TV_ + vg * 8) * KDIM + d;
        unsigned short* valT = (unsigned short*)ws + VALT_U16_OFF;
        u8v o;
        #pragma unroll
        for (int j = 0; j < 8; ++j) o[j] = f2bf(src[(size_t)j * KDIM]);
        *(u8v*)(valT + ((size_t)b * D_ + d) * TV_ + vg * 8) = o;
        return;
    }

    __shared__ unsigned short Al[2][32][40];
    __shared__ unsigned short Bl[2][32][40];

    const int proj = job;
    const int x    = blockIdx.x;

    int m0, n0;
    if (proj == 0) { m0 = (x >> 3) * 32; n0 = (x & 7) * 32; }   // 32 x 8
    else           { m0 = (x & 7) * 32;  n0 = (x >> 3) * 32; }  // 8 x 32

    const int drow = tid >> 3;        // direct-path row 0..31
    const int dk   = (tid & 7) * 4;   // direct-path k offset
    const int tcol = drow;
    const int tk   = dk;

    const float* dptr = (proj ? values + (size_t)(n0 + drow) * KDIM
                              : query  + (size_t)(m0 + drow) * KDIM) + dk;
    const float* tptr = (proj ? W2 + (m0 + tcol) : W1 + (n0 + tcol))
                        + (size_t)tk * U_;

    f4 d0;
    float tv0, tv1, tv2, tv3;

#define LOADR(S)                                                        \
    do {                                                                \
        d0 = *(const f4*)(dptr + (size_t)(S) * 32);                     \
        const float* tp = tptr + (size_t)(S) * 32 * U_;                 \
        tv0 = tp[0]; tv1 = tp[U_]; tv2 = tp[2 * U_]; tv3 = tp[3 * U_];  \
    } while (0)

#define WRITEB(BUF)                                                     \
    do {                                                                \
        u4v dd, tt;                                                     \
        dd[0] = f2bf(d0[0]); dd[1] = f2bf(d0[1]);                       \
        dd[2] = f2bf(d0[2]); dd[3] = f2bf(d0[3]);                       \
        tt[0] = f2bf(tv0);   tt[1] = f2bf(tv1);                         \
        tt[2] = f2bf(tv2);   tt[3] = f2bf(tv3);                         \
        unsigned short* ddst = proj ? &Bl[BUF][drow][dk] : &Al[BUF][drow][dk]; \
        unsigned short* tdst = proj ? &Al[BUF][tcol][tk] : &Bl[BUF][tcol][tk]; \
        *(u4v*)ddst = dd;                                               \
        *(u4v*)tdst = tt;                                               \
    } while (0)

    f4 acc = {};

    const int w    = tid >> 6;        // wave 0..3
    const int l    = tid & 63;
    const int fr   = l & 15;
    const int fk   = (l >> 4) * 8;
    const int band = (w & 1) * 16;    // row band
    const int colh = (w >> 1) * 16;   // col half

    LOADR(0);
    WRITEB(0);

    for (int s = 0; s < 16; ++s) {
        __syncthreads();
        if (s + 1 < 16) LOADR(s + 1);
        {
            const int bu = s & 1;
            s8v af = *(const s8v*)&Al[bu][band + fr][fk];
            s8v bf = *(const s8v*)&Bl[bu][colh + fr][fk];
            acc = __builtin_amdgcn_mfma_f32_16x16x32_bf16(af, bf, acc, 0, 0, 0);
        }
        if (s + 1 < 16) WRITEB((s + 1) & 1);
    }
#undef LOADR
#undef WRITEB

    // C/D: col = l&15, row = (l>>4)*4 + r
    const int orow = m0 + band + (l >> 4) * 4;
    const int ocol = n0 + colh + (l & 15);

    if (proj == 0) {
        float* E = ws;                // Eq[1024][256] fp32
        const float bias = b1[ocol];
        #pragma unroll
        for (int r = 0; r < 4; ++r)
            E[(size_t)(orow + r) * U_ + ocol] =
                EXP2F((acc[r] + bias) * C2LOG2E);
    } else {
        unsigned short* E = (unsigned short*)ws + EVT_U16_OFF;  // EvT bf16
        #pragma unroll
        for (int r = 0; r < 4; ++r)
            E[(size_t)(orow + r) * MROWS + ocol] =
                f2bf(EXP2F((acc[r] + b2[orow + r]) * C2LOG2E));
    }
}

// ---------------- score + softmax ----------------
// Block = (b, 2 q-rows), 256 threads. Thread owns v = tid.
// EvT now bf16 (half the bytes); attn written to out (f32) AND ws (bf16).
__global__ __launch_bounds__(256) void score_softmax(
    const float* __restrict__ Vw, float* __restrict__ ws,
    float* __restrict__ out)
{
    __shared__ float redmin[4][2];
    __shared__ float redsum[4][2];

    const int tid = threadIdx.x;
    const int b  = blockIdx.y;
    const int q0 = blockIdx.x * 2;

    const float* eq0 = ws + (size_t)(b * TQ_ + q0) * U_;            // uniform
    const float* eq1 = eq0 + U_;                                    // uniform
    const unsigned short* evp =
        (const unsigned short*)ws + EVT_U16_OFF + (size_t)b * TV_ + tid;
    float* attn = out + (size_t)B_ * TQ_ * D_ + (size_t)(b * TQ_ + q0) * TV_;
    unsigned short* attnbf =
        (unsigned short*)ws + ATTN_U16_OFF + (size_t)(b * TQ_ + q0) * TV_;

    float evA[8], evB[8];
    #pragma unroll
    for (int i = 0; i < 8; ++i) evA[i] = bf2f(evp[(size_t)i * MROWS]);

    f2 p = {0.f, 0.f};
    const f2 one = {1.0f, 1.0f};

#define SGRP(BUF, G)                                                    \
    _Pragma("unroll")                                                   \
    for (int i = 0; i < 8; ++i) {                                       \
        const int u = (G) * 8 + i;                                      \
        f2 eq = {eq0[u], eq1[u]};      /* s_load pair */                \
        f2 ev2 = {BUF[i], BUF[i]};                                      \
        f2 den = eq * ev2 + one;       /* v_pk_fma_f32 */               \
        f2 r = {RCPF(den.x), RCPF(den.y)};                              \
        f2 wv = {Vw[u], Vw[u]};        /* s_load */                     \
        p = wv * r + p;                /* v_pk_fma_f32 */               \
    }

    #pragma unroll
    for (int g = 0; g < 32; g += 2) {
        #pragma unroll
        for (int i = 0; i < 8; ++i)
            evB[i] = bf2f(evp[(size_t)((g + 1) * 8 + i) * MROWS]);
        SGRP(evA, g)
        if (g + 2 < 32) {
            #pragma unroll
            for (int i = 0; i < 8; ++i)
                evA[i] = bf2f(evp[(size_t)((g + 2) * 8 + i) * MROWS]);
        }
        SGRP(evB, g + 1)
    }
#undef SGRP

    // softmax over v (score = const - 2p: max score = min p)
    const int w = tid >> 6, lane = tid & 63;
    float m0 = p.x, m1 = p.y;
    #pragma unroll
    for (int off = 32; off; off >>= 1) {
        m0 = fminf(m0, __shfl_xor(m0, off));
        m1 = fminf(m1, __shfl_xor(m1, off));
    }
    if (lane == 0) { redmin[w][0] = m0; redmin[w][1] = m1; }
    __syncthreads();
    m0 = fminf(fminf(redmin[0][0], redmin[1][0]),
               fminf(redmin[2][0], redmin[3][0]));
    m1 = fminf(fminf(redmin[0][1], redmin[1][1]),
               fminf(redmin[2][1], redmin[3][1]));

    float e0 = EXP2F((m0 - p.x) * C2LOG2E);
    float e1 = EXP2F((m1 - p.y) * C2LOG2E);

    float s0 = e0, s1 = e1;
    #pragma unroll
    for (int off = 32; off; off >>= 1) {
        s0 += __shfl_xor(s0, off);
        s1 += __shfl_xor(s1, off);
    }
    if (lane == 0) { redsum[w][0] = s0; redsum[w][1] = s1; }
    __syncthreads();
    s0 = redsum[0][0] + redsum[1][0] + redsum[2][0] + redsum[3][0];
    s1 = redsum[0][1] + redsum[1][1] + redsum[2][1] + redsum[3][1];

    const float a0 = e0 * (1.0f / s0);    // exact division
    const float a1 = e1 * (1.0f / s1);
    attn[tid]        = a0;
    attn[TV_ + tid]  = a1;
    attnbf[tid]        = f2bf(a0);
    attnbf[TV_ + tid]  = f2bf(a1);
}

// ---------------- context = attn @ values, bf16 MFMA, BK=64 ----------------
// C[q][d] = sum_v attn[q][v] * valT[d][v].  32x32 tile, K=256 in 4 steps of
// 64. Staging = pure u8v copies (bf16 sources, no cvt). LDS rows padded to
// 72 elems (144B = 9x16B: aligned b128, 2-way-free banks). 2 MFMA/wave/step.
__global__ __launch_bounds__(256) void ctx_mfma(
    const float* __restrict__ ws_ro, float* __restrict__ out)
{
    __shared__ unsigned short Al[2][32][72];
    __shared__ unsigned short Bl[2][32][72];

    const int tid = threadIdx.x;
    const int b   = blockIdx.y;
    const int x   = blockIdx.x;
    const int m0  = (x >> 4) * 32;    // q-tile (8)
    const int n0  = (x & 15) * 32;    // d-tile (16)

    const int row  = tid >> 3;        // 0..31
    const int koff = (tid & 7) * 8;   // 0..56

    const unsigned short* attnbf =
        (const unsigned short*)ws_ro + ATTN_U16_OFF;
    const unsigned short* valT =
        (const unsigned short*)ws_ro + VALT_U16_OFF;

    const unsigned short* asrc =
        attnbf + ((size_t)(b * TQ_ + m0 + row)) * TV_ + koff;
    const unsigned short* bsrc =
        valT + ((size_t)(b * D_ + n0 + row)) * TV_ + koff;

    u8v a8, b8;

#define LOADC(S)                                                        \
    do {                                                                \
        a8 = *(const u8v*)(asrc + (S) * 64);                            \
        b8 = *(const u8v*)(bsrc + (S) * 64);                            \
    } while (0)

#define WRITEC(BUF)                                                     \
    do {                                                                \
        *(u8v*)&Al[BUF][row][koff] = a8;                                \
        *(u8v*)&Bl[BUF][row][koff] = b8;                                \
    } while (0)

    f4 acc = {};

    const int w    = tid >> 6;
    const int l    = tid & 63;
    const int fr   = l & 15;
    const int fk   = (l >> 4) * 8;
    const int band = (w & 1) * 16;
    const int colh = (w >> 1) * 16;

    LOADC(0);
    WRITEC(0);

    for (int s = 0; s < 4; ++s) {     // K = 256, BK = 64
        __syncthreads();
        if (s + 1 < 4) LOADC(s + 1);
        {
            const int bu = s & 1;
            s8v af0 = *(const s8v*)&Al[bu][band + fr][fk];
            s8v af1 = *(const s8v*)&Al[bu][band + fr][fk + 32];
            s8v bf0 = *(const s8v*)&Bl[bu][colh + fr][fk];
            s8v bf1 = *(const s8v*)&Bl[bu][colh + fr][fk + 32];
            acc = __builtin_amdgcn_mfma_f32_16x16x32_bf16(af0, bf0, acc, 0, 0, 0);
            acc = __builtin_amdgcn_mfma_f32_16x16x32_bf16(af1, bf1, acc, 0, 0, 0);
        }
        if (s + 1 < 4) WRITEC((s + 1) & 1);
    }
#undef LOADC
#undef WRITEC

    const int orow = m0 + band + (l >> 4) * 4;
    const int ocol = n0 + colh + (l & 15);
    float* C = out + (size_t)b * TQ_ * D_;

    #pragma unroll
    for (int r = 0; r < 4; ++r)
        C[(size_t)(orow + r) * D_ + ocol] = acc[r];
}

extern "C" void kernel_launch(void* const* d_in, const int* in_sizes, int n_in,
                              void* d_out, int out_size, void* d_ws, size_t ws_size,
                              hipStream_t stream) {
    const float* query  = (const float*)d_in[0];
    const float* values = (const float*)d_in[1];
    const float* W1     = (const float*)d_in[2];
    const float* b1     = (const float*)d_in[3];
    const float* W2     = (const float*)d_in[4];
    const float* b2     = (const float*)d_in[5];
    const float* Vw     = (const float*)d_in[6];
    float* out = (float*)d_out;
    float* ws  = (float*)d_ws;

    proj_mfma<<<dim3(256, 3), 256, 0, stream>>>(query, values, W1, b1, W2, b2, ws);
    score_softmax<<<dim3(TQ_ / 2, B_), 256, 0, stream>>>(Vw, ws, out);
    ctx_mfma<<<dim3(128, B_), 256, 0, stream>>>(ws, out);
}

// Round 15
// 36.721 us; speedup vs baseline: 9.2299x; 1.0564x over previous
//
#include <hip/hip_runtime.h>
#include <math.h>

// Bahdanau attention, fp32. B=4, TQ=TV=256, H=D=512, U=256.
// out = [context (4*256*512)] ++ [attn (4*256*256)]
//
// tanh(x) = 1 - 2/(e^{2x}+1); e^{2(q+v)} = e^{2q}*e^{2v}.
// Ledger: C~21.5 fixed | proj 6.6 | score 0.9 | ctx ~4-9.
// R15: proj rebuilt as single-stage full-K LDS GEMM. Replays run on a
// scrubbed L2 (256MB poison fill), so R13/R14 showed per-K-step cold-miss
// latency dominates, not occupancy. Now: ONE load burst (128 values in
// flight/thread) -> pack bf16 -> ONE barrier -> 16 MFMA steps pure-LDS,
// no barriers. 64KB LDS (2 blocks/CU), XOR-swizzled 16B units (G4).

typedef float f4 __attribute__((ext_vector_type(4)));
typedef float f2 __attribute__((ext_vector_type(2)));
typedef __attribute__((ext_vector_type(8))) short s8v;            // 8 bf16
typedef __attribute__((ext_vector_type(8))) unsigned short u8v;   // 8 bf16

#define B_    4
#define TQ_   256
#define TV_   256
#define D_    512
#define U_    256
#define KDIM  512          // H == D == 512
#define MROWS 1024         // B*TQ == B*TV

#define C2LOG2E 2.8853900817779268f   // 2*log2(e)

// ws layout: Eq f32 [1024][256] @ u16-elem 0 (1MB)
//            EvT bf16 [256 u][1024 vg] @ 1MB
//            attnbf bf16 [4][256 q][256 v] @ 1.5MB
//            valT bf16 [4][512 d][256 v] @ 2MB
#define EVT_U16_OFF   524288
#define ATTN_U16_OFF  786432
#define VALT_U16_OFF 1048576

#if __has_builtin(__builtin_amdgcn_exp2f)
#define EXP2F(x) __builtin_amdgcn_exp2f(x)
#else
#define EXP2F(x) exp2f(x)
#endif
#if __has_builtin(__builtin_amdgcn_rcpf)
#define RCPF(x) __builtin_amdgcn_rcpf(x)
#else
#define RCPF(x) (1.0f / (x))
#endif

__device__ __forceinline__ unsigned short f2bf(float f) {   // RNE f32->bf16
    union { float f; unsigned u; } v; v.f = f;
    return (unsigned short)((v.u + 0x7FFF + ((v.u >> 16) & 1)) >> 16);
}
__device__ __forceinline__ float bf2f(unsigned short h) {
    union { unsigned u; float f; } v; v.u = (unsigned)h << 16;
    return v.f;
}
__device__ __forceinline__ u8v pack8(const f4 a, const f4 b) {
    u8v o;
    o[0] = f2bf(a[0]); o[1] = f2bf(a[1]); o[2] = f2bf(a[2]); o[3] = f2bf(a[3]);
    o[4] = f2bf(b[0]); o[5] = f2bf(b[1]); o[6] = f2bf(b[2]); o[7] = f2bf(b[3]);
    return o;
}

// ---------------- proj GEMMs, single-stage full-K LDS ----------------
// blockIdx.y: 0 -> Eq (f32), 1 -> EvT (bf16), 2 -> valT transpose.
// 32x32 tile, K=512 entirely in LDS. LDS = 2 x [32 rows][64 16B-units]
// = 64KB, XOR-swizzled (unit ^= row&7) -> <=2-way bank aliasing (free).
// Staging: direct path 16xf4 coalesced rows; gather path 64 coalesced
// strided dwords (lane-consecutive cols). All loads issued in one burst.
// K-loop: 16 x (2 ds_read_b128 + 1 MFMA), no barriers, no global ops.
__global__ __launch_bounds__(256) void proj_mfma(
    const float* __restrict__ query, const float* __restrict__ values,
    const float* __restrict__ W1, const float* __restrict__ b1,
    const float* __restrict__ W2, const float* __restrict__ b2,
    float* __restrict__ ws)
{
    const int tid = threadIdx.x;
    const int job = blockIdx.y;

    if (job == 2) {
        // valT[b][d][v] = bf16(values[b][v][d]). Coalesced reads, u8v writes.
        const int idx = blockIdx.x * 256 + tid;   // 0..65535
        const int d   = idx & 511;
        const int vg  = (idx >> 9) & 31;          // v-group of 8
        const int b   = idx >> 14;
        const float* src = values + ((size_t)b * TV_ + vg * 8) * KDIM + d;
        unsigned short* valT = (unsigned short*)ws + VALT_U16_OFF;
        u8v o;
        #pragma unroll
        for (int j = 0; j < 8; ++j) o[j] = f2bf(src[(size_t)j * KDIM]);
        *(u8v*)(valT + ((size_t)b * D_ + d) * TV_ + vg * 8) = o;
        return;
    }

    __shared__ u8v Al[32][64];
    __shared__ u8v Bl[32][64];

    const int proj = job;
    const int x    = blockIdx.x;

    int m0, n0;
    if (proj == 0) { m0 = (x >> 3) * 32; n0 = (x & 7) * 32; }   // 32 x 8
    else           { m0 = (x & 7) * 32;  n0 = (x >> 3) * 32; }  // 8 x 32

    // direct path: row = tid>>3 (0..31), 64 consecutive k @ unit base duc
    const int drow = tid >> 3;
    const int duc  = (tid & 7) * 8;   // 16B-unit base (8 units = 64 elems)
    const float* dsrc = (proj ? values + (size_t)(n0 + drow) * KDIM
                              : query  + (size_t)(m0 + drow) * KDIM) + duc * 8;

    // gather path: col = tid&31 (lane-consecutive -> coalesced), 64 k's
    const int gcol = tid & 31;
    const int gk0  = (tid >> 5) * 64;
    const float* gsrc = (proj ? W2 + (m0 + gcol) : W1 + (n0 + gcol))
                        + (size_t)gk0 * U_;

    u8v (*DIR)[64] = proj ? Bl : Al;   // proj0: A=query rows, B=W1 cols
    u8v (*GAT)[64] = proj ? Al : Bl;   // proj1: B=values rows, A=W2 cols

    // ---- one load burst: 16 f4 + 64 dwords in flight per thread
    f4 dv[16];
    #pragma unroll
    for (int j = 0; j < 16; ++j) dv[j] = *(const f4*)(dsrc + j * 4);
    float gv[64];
    #pragma unroll
    for (int j = 0; j < 64; ++j) gv[j] = gsrc[(size_t)j * U_];

    // ---- pack bf16 + swizzled LDS writes
    #pragma unroll
    for (int j = 0; j < 8; ++j)
        DIR[drow][(duc + j) ^ (drow & 7)] = pack8(dv[2 * j], dv[2 * j + 1]);
    #pragma unroll
    for (int g = 0; g < 8; ++g) {
        u8v o;
        #pragma unroll
        for (int j = 0; j < 8; ++j) o[j] = f2bf(gv[g * 8 + j]);
        GAT[gcol][((gk0 >> 3) + g) ^ (gcol & 7)] = o;
    }
    __syncthreads();

    // ---- K-loop: pure LDS + MFMA, no barriers
    f4 acc = {};
    const int w    = tid >> 6;
    const int l    = tid & 63;
    const int fr   = l & 15;
    const int fko  = l >> 4;          // 16B-unit offset within 32-k step
    const int band = (w & 1) * 16;
    const int colh = (w >> 1) * 16;
    const int ar   = band + fr;
    const int br   = colh + fr;

    #pragma unroll
    for (int s = 0; s < 16; ++s) {
        s8v af = *(const s8v*)&Al[ar][(fko + 4 * s) ^ (ar & 7)];
        s8v bf = *(const s8v*)&Bl[br][(fko + 4 * s) ^ (br & 7)];
        acc = __builtin_amdgcn_mfma_f32_16x16x32_bf16(af, bf, acc, 0, 0, 0);
    }

    // ---- epilogue (C/D: col=l&15, row=(l>>4)*4+r)
    const int orow = m0 + band + (l >> 4) * 4;
    const int ocol = n0 + colh + (l & 15);

    if (proj == 0) {
        float* E = ws;                // Eq[1024][256] fp32
        const float bias = b1[ocol];
        #pragma unroll
        for (int r = 0; r < 4; ++r)
            E[(size_t)(orow + r) * U_ + ocol] =
                EXP2F((acc[r] + bias) * C2LOG2E);
    } else {
        unsigned short* E = (unsigned short*)ws + EVT_U16_OFF;  // EvT bf16
        #pragma unroll
        for (int r = 0; r < 4; ++r)
            E[(size_t)(orow + r) * MROWS + ocol] =
                f2bf(EXP2F((acc[r] + b2[orow + r]) * C2LOG2E));
    }
}

// ---------------- score + softmax (unchanged from R14, ~1us) ----------------
__global__ __launch_bounds__(256) void score_softmax(
    const float* __restrict__ Vw, float* __restrict__ ws,
    float* __restrict__ out)
{
    __shared__ float redmin[4][2];
    __shared__ float redsum[4][2];

    const int tid = threadIdx.x;
    const int b  = blockIdx.y;
    const int q0 = blockIdx.x * 2;

    const float* eq0 = ws + (size_t)(b * TQ_ + q0) * U_;            // uniform
    const float* eq1 = eq0 + U_;                                    // uniform
    const unsigned short* evp =
        (const unsigned short*)ws + EVT_U16_OFF + (size_t)b * TV_ + tid;
    float* attn = out + (size_t)B_ * TQ_ * D_ + (size_t)(b * TQ_ + q0) * TV_;
    unsigned short* attnbf =
        (unsigned short*)ws + ATTN_U16_OFF + (size_t)(b * TQ_ + q0) * TV_;

    float evA[8], evB[8];
    #pragma unroll
    for (int i = 0; i < 8; ++i) evA[i] = bf2f(evp[(size_t)i * MROWS]);

    f2 p = {0.f, 0.f};
    const f2 one = {1.0f, 1.0f};

#define SGRP(BUF, G)                                                    \
    _Pragma("unroll")                                                   \
    for (int i = 0; i < 8; ++i) {                                       \
        const int u = (G) * 8 + i;                                      \
        f2 eq = {eq0[u], eq1[u]};      /* s_load pair */                \
        f2 ev2 = {BUF[i], BUF[i]};                                      \
        f2 den = eq * ev2 + one;       /* v_pk_fma_f32 */               \
        f2 r = {RCPF(den.x), RCPF(den.y)};                              \
        f2 wv = {Vw[u], Vw[u]};        /* s_load */                     \
        p = wv * r + p;                /* v_pk_fma_f32 */               \
    }

    #pragma unroll
    for (int g = 0; g < 32; g += 2) {
        #pragma unroll
        for (int i = 0; i < 8; ++i)
            evB[i] = bf2f(evp[(size_t)((g + 1) * 8 + i) * MROWS]);
        SGRP(evA, g)
        if (g + 2 < 32) {
            #pragma unroll
            for (int i = 0; i < 8; ++i)
                evA[i] = bf2f(evp[(size_t)((g + 2) * 8 + i) * MROWS]);
        }
        SGRP(evB, g + 1)
    }
#undef SGRP

    // softmax over v (score = const - 2p: max score = min p)
    const int w = tid >> 6, lane = tid & 63;
    float m0 = p.x, m1 = p.y;
    #pragma unroll
    for (int off = 32; off; off >>= 1) {
        m0 = fminf(m0, __shfl_xor(m0, off));
        m1 = fminf(m1, __shfl_xor(m1, off));
    }
    if (lane == 0) { redmin[w][0] = m0; redmin[w][1] = m1; }
    __syncthreads();
    m0 = fminf(fminf(redmin[0][0], redmin[1][0]),
               fminf(redmin[2][0], redmin[3][0]));
    m1 = fminf(fminf(redmin[0][1], redmin[1][1]),
               fminf(redmin[2][1], redmin[3][1]));

    float e0 = EXP2F((m0 - p.x) * C2LOG2E);
    float e1 = EXP2F((m1 - p.y) * C2LOG2E);

    float s0 = e0, s1 = e1;
    #pragma unroll
    for (int off = 32; off; off >>= 1) {
        s0 += __shfl_xor(s0, off);
        s1 += __shfl_xor(s1, off);
    }
    if (lane == 0) { redsum[w][0] = s0; redsum[w][1] = s1; }
    __syncthreads();
    s0 = redsum[0][0] + redsum[1][0] + redsum[2][0] + redsum[3][0];
    s1 = redsum[0][1] + redsum[1][1] + redsum[2][1] + redsum[3][1];

    const float a0 = e0 * (1.0f / s0);    // exact division
    const float a1 = e1 * (1.0f / s1);
    attn[tid]        = a0;
    attn[TV_ + tid]  = a1;
    attnbf[tid]        = f2bf(a0);
    attnbf[TV_ + tid]  = f2bf(a1);
}

// ---------------- context = attn @ values, bf16 MFMA, BK=64 (R14) ----------
__global__ __launch_bounds__(256) void ctx_mfma(
    const float* __restrict__ ws_ro, float* __restrict__ out)
{
    __shared__ unsigned short Al[2][32][72];
    __shared__ unsigned short Bl[2][32][72];

    const int tid = threadIdx.x;
    const int b   = blockIdx.y;
    const int x   = blockIdx.x;
    const int m0  = (x >> 4) * 32;    // q-tile (8)
    const int n0  = (x & 15) * 32;    // d-tile (16)

    const int row  = tid >> 3;        // 0..31
    const int koff = (tid & 7) * 8;   // 0..56

    const unsigned short* attnbf =
        (const unsigned short*)ws_ro + ATTN_U16_OFF;
    const unsigned short* valT =
        (const unsigned short*)ws_ro + VALT_U16_OFF;

    const unsigned short* asrc =
        attnbf + ((size_t)(b * TQ_ + m0 + row)) * TV_ + koff;
    const unsigned short* bsrc =
        valT + ((size_t)(b * D_ + n0 + row)) * TV_ + koff;

    u8v a8, b8;

#define LOADC(S)                                                        \
    do {                                                                \
        a8 = *(const u8v*)(asrc + (S) * 64);                            \
        b8 = *(const u8v*)(bsrc + (S) * 64);                            \
    } while (0)

#define WRITEC(BUF)                                                     \
    do {                                                                \
        *(u8v*)&Al[BUF][row][koff] = a8;                                \
        *(u8v*)&Bl[BUF][row][koff] = b8;                                \
    } while (0)

    f4 acc = {};

    const int w    = tid >> 6;
    const int l    = tid & 63;
    const int fr   = l & 15;
    const int fk   = (l >> 4) * 8;
    const int band = (w & 1) * 16;
    const int colh = (w >> 1) * 16;

    LOADC(0);
    WRITEC(0);

    for (int s = 0; s < 4; ++s) {     // K = 256, BK = 64
        __syncthreads();
        if (s + 1 < 4) LOADC(s + 1);
        {
            const int bu = s & 1;
            s8v af0 = *(const s8v*)&Al[bu][band + fr][fk];
            s8v af1 = *(const s8v*)&Al[bu][band + fr][fk + 32];
            s8v bf0 = *(const s8v*)&Bl[bu][colh + fr][fk];
            s8v bf1 = *(const s8v*)&Bl[bu][colh + fr][fk + 32];
            acc = __builtin_amdgcn_mfma_f32_16x16x32_bf16(af0, bf0, acc, 0, 0, 0);
            acc = __builtin_amdgcn_mfma_f32_16x16x32_bf16(af1, bf1, acc, 0, 0, 0);
        }
        if (s + 1 < 4) WRITEC((s + 1) & 1);
    }
#undef LOADC
#undef WRITEC

    const int orow = m0 + band + (l >> 4) * 4;
    const int ocol = n0 + colh + (l & 15);
    float* C = out + (size_t)b * TQ_ * D_;

    #pragma unroll
    for (int r = 0; r < 4; ++r)
        C[(size_t)(orow + r) * D_ + ocol] = acc[r];
}

extern "C" void kernel_launch(void* const* d_in, const int* in_sizes, int n_in,
                              void* d_out, int out_size, void* d_ws, size_t ws_size,
                              hipStream_t stream) {
    const float* query  = (const float*)d_in[0];
    const float* values = (const float*)d_in[1];
    const float* W1     = (const float*)d_in[2];
    const float* b1     = (const float*)d_in[3];
    const float* W2     = (const float*)d_in[4];
    const float* b2     = (const float*)d_in[5];
    const float* Vw     = (const float*)d_in[6];
    float* out = (float*)d_out;
    float* ws  = (float*)d_ws;

    proj_mfma<<<dim3(256, 3), 256, 0, stream>>>(query, values, W1, b1, W2, b2, ws);
    score_softmax<<<dim3(TQ_ / 2, B_), 256, 0, stream>>>(Vw, ws, out);
    ctx_mfma<<<dim3(128, B_), 256, 0, stream>>>(ws, out);
}